// Round 1
// baseline (95.417 us; speedup 1.0000x reference)
//
#include <hip/hip_runtime.h>
#include <math.h>

#define NN 256
#define XX 256
#define TT 3
#define KK 64
#define AA 193          // 3*K+1
#define EPSF 1e-9f
#define NPART 256
#define WPB 4           // waves (pairs) per block in k_pairs
#define PB 192          // ceil((X*T-1)/WPB) = ceil(767/4)

// ws layout (bytes):
// [0, 2048)              double part[256]
// [2048, 3072)           int nsel[256]
// [3072, 4096)           int ncols[256]
// [4096, 4096+262144)    int S[256][256]   (full `order` per n)
// [266240, 331776)       int Ck[256][64]   (full `corder` per n)

__global__ __launch_bounds__(256) void k_meta(const float* __restrict__ gt,
                                              int* __restrict__ nselArr,
                                              int* __restrict__ ncolsArr,
                                              int* __restrict__ S,
                                              int* __restrict__ Ck) {
    int n = blockIdx.x;
    int tid = threadIdx.x;
    int lane = tid & 63;
    int wave = tid >> 6;

    __shared__ int s_S[XX];
    __shared__ int s_cnt[4];
    __shared__ float s_red[256];
    __shared__ int s_nsel;

    // ---- phase 1: sel + stable partition (the `order` array) ----
    int x = tid;
    float gc = gt[((size_t)(n * XX + x) * TT + 0) * AA + (AA - 1)];
    bool selx = gc > 0.0f;
    unsigned long long bal = __ballot(selx);
    if (lane == 0) s_cnt[wave] = __popcll(bal);
    __syncthreads();
    int c0 = s_cnt[0], c1 = s_cnt[1], c2 = s_cnt[2], c3 = s_cnt[3];
    int nsel_n = c0 + c1 + c2 + c3;
    int selbase = (wave > 0 ? c0 : 0) + (wave > 1 ? c1 : 0) + (wave > 2 ? c2 : 0);
    unsigned long long ltmask = (1ull << lane) - 1ull;
    int pos;
    if (selx) pos = selbase + __popcll(bal & ltmask);
    else      pos = nsel_n + (64 * wave - selbase) + __popcll((~bal) & ltmask);
    s_S[pos] = x;
    if (tid == 0) { s_nsel = nsel_n; nselArr[n] = nsel_n; }
    __syncthreads();
    S[n * XX + tid] = s_S[tid];

    // ---- phase 2: column sums over selected rows ----
    int nsl = s_nsel;
    float partial = 0.0f;
    for (int i = wave; i < nsl; i += 4) {
        int xs = s_S[i];
        size_t base = ((size_t)(n * XX + xs) * TT) * AA + 2 * KK + lane;
        partial += gt[base] + gt[base + AA] + gt[base + 2 * AA];
    }
    s_red[tid] = partial;
    __syncthreads();

    // ---- phase 3: keep + stable column partition (the `corder` array) ----
    if (tid < KK) {
        float tot = s_red[tid] + s_red[tid + 64] + s_red[tid + 128] + s_red[tid + 192];
        int nrows = nsl * TT;
        bool keep = (tot >= (float)nrows) || (tid < 5);
        unsigned long long kb = __ballot(keep);
        int nc = __popcll(kb);
        unsigned long long lt = (1ull << tid) - 1ull;
        int cpos = keep ? __popcll(kb & lt) : nc + __popcll((~kb) & lt);
        Ck[n * KK + cpos] = tid;
        if (tid == 0) ncolsArr[n] = nc;
    }
}

__global__ __launch_bounds__(256) void k_bce(const float* __restrict__ pred,
                                             const float* __restrict__ gt,
                                             double* __restrict__ part) {
    int tid = threadIdx.x;
    int lane = tid & 63;
    int gw = blockIdx.x * 4 + (tid >> 6);
    int nwaves = gridDim.x * 4;
    const int NROWS = NN * XX * TT;

    float a0 = 0.0f, a1 = 0.0f, a2 = 0.0f;
    for (int row = gw; row < NROWS; row += nwaves) {
        size_t base = (size_t)row * AA;
        float pX = pred[base + lane];
        float gX = gt[base + lane];
        float pv = pred[base + 2 * KK + lane];
        float gv = gt[base + 2 * KK + lane];
        float gc = gt[base + 3 * KK];
        a0 += gv * logf(pv + EPSF) + (1.0f - gv + EPSF) * logf(1.0f - pv + EPSF);
        a2 += fabsf(gc * gv * (pX - gX));
        if (lane == 0) {
            float pc = pred[base + 3 * KK];
            a1 += gc * logf(pc + EPSF) + (1.0f - gc) * logf(1.0f - pc + EPSF);
        }
    }
    float local = a2 - a0 * (1.0f / KK) - a1;

    __shared__ float red[256];
    red[tid] = local;
    __syncthreads();
    for (int s = 128; s > 0; s >>= 1) {
        if (tid < s) red[tid] += red[tid + s];
        __syncthreads();
    }
    if (tid == 0) atomicAdd(&part[blockIdx.x & (NPART - 1)], (double)red[0]);
}

__global__ __launch_bounds__(256) void k_pairs(const float* __restrict__ pred,
                                               const float* __restrict__ gt,
                                               const float* __restrict__ hcam_arr,
                                               const float* __restrict__ ax,
                                               const float* __restrict__ ay,
                                               const float* __restrict__ xstd,
                                               const float* __restrict__ zstd,
                                               const int* __restrict__ nselArr,
                                               const int* __restrict__ ncolsArr,
                                               const int* __restrict__ S,
                                               const int* __restrict__ Ck,
                                               double* __restrict__ part) {
    int n = blockIdx.x / PB;
    int chunk = blockIdx.x % PB;
    int tid = threadIdx.x;
    int lane = tid & 63;
    int wid = tid >> 6;
    int p = chunk * WPB + wid;

    int nsl = nselArr[n];
    int nrows = nsl * TT;

    float contrib = 0.0f;
    if (p + 1 < nrows) {
        int ncols = ncolsArr[n];
        int k = Ck[n * KK + lane];
        int r1 = p + 1;
        int x0 = S[n * XX + p / 3];  int t0 = p % 3;
        int x1 = S[n * XX + r1 / 3]; int t1 = r1 % 3;
        float inv_h = 1.0f / hcam_arr[n];
        float zs = zstd[k], xs = xstd[k], ayk = ay[k];
        size_t b0 = ((size_t)(n * XX + x0) * TT + t0) * AA;
        size_t b1 = ((size_t)(n * XX + x1) * TT + t1) * AA;
        float pz0 = pred[b0 + KK + k], gx0 = gt[b0 + k];
        float pz1 = pred[b1 + KK + k], gx1 = gt[b1 + k];
        float ax0 = ax[x0], ax1 = ax[x1];
        float Z0 = pz0 * zs, Z1 = pz1 * zs;
        float sc0 = 1.0f - Z0 * inv_h, sc1 = 1.0f - Z1 * inv_h;
        float L0 = sc0 * (gx0 * xs + ax0);
        float L1 = sc1 * (gx1 * xs + ax1);
        float Y0 = sc0 * ayk;
        // width0 from gtXg column k=0 (unscaled)
        float xstd0 = xstd[0];
        float l00 = gt[b0] * xstd0 + ax0;
        float l01 = gt[b1] * xstd0 + ax1;
        float width0 = fabsf(l01 - l00);

        float lm1 = __shfl_up(L0, 1);
        float ym1 = __shfl_up(Y0, 1);
        float y1v = __shfl(Y0, 1);
        float dYc, lc;
        if (lane == 0) {
            dYc = fabsf(y1v - Y0);
            lc = dYc;
        } else {
            dYc = fabsf(Y0 - ym1);
            float dx = L0 - lm1;
            lc = sqrtf(dx * dx + dYc * dYc);
        }
        float w = fabsf(L1 - L0) * dYc / (lc + EPSF);
        float wm1 = __shfl_up(w, 1);
        float werr = fabsf(w - (lane == 0 ? width0 : wm1));
        float dZ = fabsf(Z1 - Z0);
        if (lane < ncols) contrib = werr + dZ;
    }

    __shared__ float red[256];
    red[tid] = contrib;
    __syncthreads();
    for (int s = 128; s > 0; s >>= 1) {
        if (tid < s) red[tid] += red[tid + s];
        __syncthreads();
    }
    if (tid == 0 && red[0] != 0.0f)
        atomicAdd(&part[blockIdx.x & (NPART - 1)], (double)(5.0f * red[0]));
}

__global__ __launch_bounds__(256) void k_final(const double* __restrict__ part,
                                               float* __restrict__ out) {
    int tid = threadIdx.x;
    __shared__ double red[256];
    red[tid] = part[tid];
    __syncthreads();
    for (int s = 128; s > 0; s >>= 1) {
        if (tid < s) red[tid] += red[tid + s];
        __syncthreads();
    }
    if (tid == 0) out[0] = (float)red[0];
}

extern "C" void kernel_launch(void* const* d_in, const int* in_sizes, int n_in,
                              void* d_out, int out_size, void* d_ws, size_t ws_size,
                              hipStream_t stream) {
    const float* pred = (const float*)d_in[0];
    const float* gt   = (const float*)d_in[1];
    const float* hcam = (const float*)d_in[2];
    const float* ax   = (const float*)d_in[3];
    const float* ay   = (const float*)d_in[4];
    const float* xstd = (const float*)d_in[5];
    const float* zstd = (const float*)d_in[6];
    float* out = (float*)d_out;

    char* ws = (char*)d_ws;
    double* part = (double*)ws;
    int* nsel  = (int*)(ws + 2048);
    int* ncols = (int*)(ws + 3072);
    int* S     = (int*)(ws + 4096);
    int* Ck    = (int*)(ws + 4096 + NN * XX * 4);

    hipMemsetAsync(part, 0, NPART * sizeof(double), stream);
    hipLaunchKernelGGL(k_meta, dim3(NN), dim3(256), 0, stream, gt, nsel, ncols, S, Ck);
    hipLaunchKernelGGL(k_bce, dim3(1024), dim3(256), 0, stream, pred, gt, part);
    hipLaunchKernelGGL(k_pairs, dim3(NN * PB), dim3(256), 0, stream,
                       pred, gt, hcam, ax, ay, xstd, zstd, nsel, ncols, S, Ck, part);
    hipLaunchKernelGGL(k_final, dim3(1), dim3(256), 0, stream, part, out);
}

// Round 2
// 79.371 us; speedup vs baseline: 1.2022x; 1.2022x over previous
//
#include <hip/hip_runtime.h>
#include <math.h>

#define NN 256
#define XX 256
#define TT 3
#define KK 64
#define AA 193          // 3*K+1
#define EPSF 1e-9f
#define NPART 256
#define WPB 4           // waves (pairs) per block in k_pairs
#define PB 192          // ceil((X*T-1)/WPB) = ceil(767/4)

// ws layout (bytes):
// [0, 2048)              double part[256]
// [2048, 3072)           int nsel[256]
// [3072, 4096)           int ncols[256]
// [4096, 4096+262144)    int S[256][256]   (full `order` per n)
// [266240, 331776)       int Ck[256][64]   (full `corder` per n)

__global__ __launch_bounds__(256) void k_meta(const float* __restrict__ gt,
                                              int* __restrict__ nselArr,
                                              int* __restrict__ ncolsArr,
                                              int* __restrict__ S,
                                              int* __restrict__ Ck,
                                              double* __restrict__ part) {
    int n = blockIdx.x;
    int tid = threadIdx.x;
    int lane = tid & 63;
    int wave = tid >> 6;

    // zero the partial-sum buffer (consumers k_bce/k_pairs launch after us)
    if (n == 0) part[tid] = 0.0;

    __shared__ int s_S[XX];
    __shared__ int s_cnt[4];
    __shared__ float s_red[256];
    __shared__ int s_nsel;

    // ---- phase 1: sel + stable partition (the `order` array) ----
    int x = tid;
    float gc = gt[((size_t)(n * XX + x) * TT + 0) * AA + (AA - 1)];
    bool selx = gc > 0.0f;
    unsigned long long bal = __ballot(selx);
    if (lane == 0) s_cnt[wave] = __popcll(bal);
    __syncthreads();
    int c0 = s_cnt[0], c1 = s_cnt[1], c2 = s_cnt[2], c3 = s_cnt[3];
    int nsel_n = c0 + c1 + c2 + c3;
    int selbase = (wave > 0 ? c0 : 0) + (wave > 1 ? c1 : 0) + (wave > 2 ? c2 : 0);
    unsigned long long ltmask = (1ull << lane) - 1ull;
    int pos;
    if (selx) pos = selbase + __popcll(bal & ltmask);
    else      pos = nsel_n + (64 * wave - selbase) + __popcll((~bal) & ltmask);
    s_S[pos] = x;
    if (tid == 0) { s_nsel = nsel_n; nselArr[n] = nsel_n; }
    __syncthreads();
    S[n * XX + tid] = s_S[tid];

    // ---- phase 2: column sums over selected rows ----
    int nsl = s_nsel;
    float partial = 0.0f;
    for (int i = wave; i < nsl; i += 4) {
        int xs = s_S[i];
        size_t base = ((size_t)(n * XX + xs) * TT) * AA + 2 * KK + lane;
        partial += gt[base] + gt[base + AA] + gt[base + 2 * AA];
    }
    s_red[tid] = partial;
    __syncthreads();

    // ---- phase 3: keep + stable column partition (the `corder` array) ----
    if (tid < KK) {
        float tot = s_red[tid] + s_red[tid + 64] + s_red[tid + 128] + s_red[tid + 192];
        int nrows = nsl * TT;
        bool keep = (tot >= (float)nrows) || (tid < 5);
        unsigned long long kb = __ballot(keep);
        int nc = __popcll(kb);
        unsigned long long lt = (1ull << tid) - 1ull;
        int cpos = keep ? __popcll(kb & lt) : nc + __popcll((~kb) & lt);
        Ck[n * KK + cpos] = tid;
        if (tid == 0) ncolsArr[n] = nc;
    }
}

__global__ __launch_bounds__(256) void k_bce(const float* __restrict__ pred,
                                             const float* __restrict__ gt,
                                             double* __restrict__ part) {
    int tid = threadIdx.x;
    int lane = tid & 63;
    int gw = blockIdx.x * 4 + (tid >> 6);
    int nwaves = gridDim.x * 4;
    const int NROWS = NN * XX * TT;

    float a0 = 0.0f, a12 = 0.0f;
    for (int row = gw; row < NROWS; row += nwaves) {
        size_t base = (size_t)row * AA;
        float pv = pred[base + 2 * KK + lane];
        float gv = gt[base + 2 * KK + lane];
        float gc = gt[base + 3 * KK];          // wave-uniform broadcast
        a0 += gv * __logf(pv + EPSF) + (1.0f - gv + EPSF) * __logf(1.0f - pv + EPSF);
        if (lane == 0) {
            float pc = pred[base + 3 * KK];
            a12 -= gc * __logf(pc + EPSF) + (1.0f - gc) * __logf(1.0f - pc + EPSF);
        }
        if (gc > 0.0f) {                       // wave-uniform; gc is exactly 0 or 1
            float pX = pred[base + lane];
            float gX = gt[base + lane];
            a12 += gv * fabsf(pX - gX);        // == |gc*gv*(pX-gX)| when gc==1
        }
    }
    float local = a12 - a0 * (1.0f / KK);

    __shared__ float red[256];
    red[tid] = local;
    __syncthreads();
    for (int s = 128; s > 0; s >>= 1) {
        if (tid < s) red[tid] += red[tid + s];
        __syncthreads();
    }
    if (tid == 0) atomicAdd(&part[blockIdx.x & (NPART - 1)], (double)red[0]);
}

__global__ __launch_bounds__(256) void k_pairs(const float* __restrict__ pred,
                                               const float* __restrict__ gt,
                                               const float* __restrict__ hcam_arr,
                                               const float* __restrict__ ax,
                                               const float* __restrict__ ay,
                                               const float* __restrict__ xstd,
                                               const float* __restrict__ zstd,
                                               const int* __restrict__ nselArr,
                                               const int* __restrict__ ncolsArr,
                                               const int* __restrict__ S,
                                               const int* __restrict__ Ck,
                                               double* __restrict__ part) {
    int n = blockIdx.x / PB;
    int chunk = blockIdx.x % PB;
    int tid = threadIdx.x;
    int lane = tid & 63;
    int wid = tid >> 6;
    int p = chunk * WPB + wid;

    int nsl = nselArr[n];
    int nrows = nsl * TT;

    float contrib = 0.0f;
    if (p + 1 < nrows) {
        int ncols = ncolsArr[n];
        int k = Ck[n * KK + lane];
        int r1 = p + 1;
        int x0 = S[n * XX + p / 3];  int t0 = p % 3;
        int x1 = S[n * XX + r1 / 3]; int t1 = r1 % 3;
        float inv_h = 1.0f / hcam_arr[n];
        float zs = zstd[k], xs = xstd[k], ayk = ay[k];
        size_t b0 = ((size_t)(n * XX + x0) * TT + t0) * AA;
        size_t b1 = ((size_t)(n * XX + x1) * TT + t1) * AA;
        float pz0 = pred[b0 + KK + k], gx0 = gt[b0 + k];
        float pz1 = pred[b1 + KK + k], gx1 = gt[b1 + k];
        float ax0 = ax[x0], ax1 = ax[x1];
        float Z0 = pz0 * zs, Z1 = pz1 * zs;
        float sc0 = 1.0f - Z0 * inv_h, sc1 = 1.0f - Z1 * inv_h;
        float L0 = sc0 * (gx0 * xs + ax0);
        float L1 = sc1 * (gx1 * xs + ax1);
        float Y0 = sc0 * ayk;
        // width0 from gtXg column k=0 (unscaled)
        float xstd0 = xstd[0];
        float l00 = gt[b0] * xstd0 + ax0;
        float l01 = gt[b1] * xstd0 + ax1;
        float width0 = fabsf(l01 - l00);

        float lm1 = __shfl_up(L0, 1);
        float ym1 = __shfl_up(Y0, 1);
        float y1v = __shfl(Y0, 1);
        float dYc, lc;
        if (lane == 0) {
            dYc = fabsf(y1v - Y0);
            lc = dYc;
        } else {
            dYc = fabsf(Y0 - ym1);
            float dx = L0 - lm1;
            lc = sqrtf(dx * dx + dYc * dYc);
        }
        float w = fabsf(L1 - L0) * dYc / (lc + EPSF);
        float wm1 = __shfl_up(w, 1);
        float werr = fabsf(w - (lane == 0 ? width0 : wm1));
        float dZ = fabsf(Z1 - Z0);
        if (lane < ncols) contrib = werr + dZ;
    }

    __shared__ float red[256];
    red[tid] = contrib;
    __syncthreads();
    for (int s = 128; s > 0; s >>= 1) {
        if (tid < s) red[tid] += red[tid + s];
        __syncthreads();
    }
    if (tid == 0 && red[0] != 0.0f)
        atomicAdd(&part[blockIdx.x & (NPART - 1)], (double)(5.0f * red[0]));
}

__global__ __launch_bounds__(256) void k_final(const double* __restrict__ part,
                                               float* __restrict__ out) {
    int tid = threadIdx.x;
    __shared__ double red[256];
    red[tid] = part[tid];
    __syncthreads();
    for (int s = 128; s > 0; s >>= 1) {
        if (tid < s) red[tid] += red[tid + s];
        __syncthreads();
    }
    if (tid == 0) out[0] = (float)red[0];
}

extern "C" void kernel_launch(void* const* d_in, const int* in_sizes, int n_in,
                              void* d_out, int out_size, void* d_ws, size_t ws_size,
                              hipStream_t stream) {
    const float* pred = (const float*)d_in[0];
    const float* gt   = (const float*)d_in[1];
    const float* hcam = (const float*)d_in[2];
    const float* ax   = (const float*)d_in[3];
    const float* ay   = (const float*)d_in[4];
    const float* xstd = (const float*)d_in[5];
    const float* zstd = (const float*)d_in[6];
    float* out = (float*)d_out;

    char* ws = (char*)d_ws;
    double* part = (double*)ws;
    int* nsel  = (int*)(ws + 2048);
    int* ncols = (int*)(ws + 3072);
    int* S     = (int*)(ws + 4096);
    int* Ck    = (int*)(ws + 4096 + NN * XX * 4);

    hipLaunchKernelGGL(k_meta, dim3(NN), dim3(256), 0, stream, gt, nsel, ncols, S, Ck, part);
    hipLaunchKernelGGL(k_bce, dim3(2048), dim3(256), 0, stream, pred, gt, part);
    hipLaunchKernelGGL(k_pairs, dim3(NN * PB), dim3(256), 0, stream,
                       pred, gt, hcam, ax, ay, xstd, zstd, nsel, ncols, S, Ck, part);
    hipLaunchKernelGGL(k_final, dim3(1), dim3(256), 0, stream, part, out);
}